// Round 11
// baseline (257.966 us; speedup 1.0000x reference)
//
#include <hip/hip_runtime.h>
#include <hip/hip_bf16.h>

typedef __bf16 bf16_t;
typedef bf16_t bf16x8 __attribute__((ext_vector_type(8)));
typedef float floatx4 __attribute__((ext_vector_type(4)));

#define BB 4
#define NN 4096
#define QDIM 1024
#define HEADS 8
#define DHEAD 64
#define HID 512
#define ROWS (BB*NN)      /* 16384 */
#define QKV_LD 1536

__device__ __forceinline__ float b2f(bf16_t v){ return (float)v; }
__device__ __forceinline__ bf16_t f2b(float v){ return (bf16_t)v; }

__device__ __forceinline__ bf16x8 load8(const bf16_t* p) { return *(const bf16x8*)p; }
__device__ __forceinline__ bf16x8 load8(const float* p) {
  float4 a = *(const float4*)p;
  float4 b = *(const float4*)(p + 4);
  bf16x8 r;
  r[0]=f2b(a.x); r[1]=f2b(a.y); r[2]=f2b(a.z); r[3]=f2b(a.w);
  r[4]=f2b(b.x); r[5]=f2b(b.y); r[6]=f2b(b.z); r[7]=f2b(b.w);
  return r;
}
__device__ __forceinline__ void store_out(bf16_t* p, float v){ *p = f2b(v); }
__device__ __forceinline__ void store_out(float*  p, float v){ *p = v; }

// async global -> LDS, 16B per lane. LDS base must be wave-uniform.
__device__ __forceinline__ void gll16(const void* g, void* l) {
  __builtin_amdgcn_global_load_lds((const __attribute__((address_space(1))) void*)g,
                                   (__attribute__((address_space(3))) void*)l,
                                   16, 0, 0);
}

// ---------------- workspace layout (bytes) ---------------------------------
// xb (bf16 x, 33.5MB) ALIASES [OFF_CP, OFF_CP+33.5MB): cPart/sPart/W2T are
// written only AFTER the QKV GEMM has consumed xb. Max ws use ~87MB.
static constexpr size_t OFF_QKV = 0;                      // 16384*1536*2 = 50331648
static constexpr size_t OFF_WT  = 50331648;               // 1536*1024*2  = 3145728
static constexpr size_t OFF_CP  = OFF_WT + 3145728;       // 16*32*4096*4 = 8388608
static constexpr size_t OFF_SPT = OFF_CP + 8388608;       // 16*32*64*4   = 131072
static constexpr size_t OFF_W2  = OFF_SPT + 131072;       // 4*1024*512*2 = 4194304
static constexpr size_t OFF_XB  = OFF_CP;                 // alias (see above)

// ------ prep: x f32->bf16 downconvert + QKV weight transpose (one launch) --
// blocks [0,8192): to_bf16 of x; blocks [8192,8576): 64x64 transpose tiles.
__global__ __launch_bounds__(256) void prep(
    const float* __restrict__ x,
    const float* __restrict__ Wq, const float* __restrict__ Wk,
    const float* __restrict__ Wv,
    bf16_t* __restrict__ xb, bf16_t* __restrict__ WTall) {
  __shared__ bf16_t T[64][68];
  int t = threadIdx.x;
  if (blockIdx.x < 8192) {
    size_t i = ((size_t)blockIdx.x * 256 + t) * 8;
    *(bf16x8*)&xb[i] = load8(&x[i]);
    return;
  }
  int bid = blockIdx.x - 8192;         // 0..383
  int z = bid >> 7;                    // 0..2
  int rem = bid & 127;
  int r0 = (rem >> 3) * 64, c0 = (rem & 7) * 64;
  const float* in = z == 0 ? Wq : (z == 1 ? Wk : Wv);
  bf16_t* o = WTall + (size_t)z * HID * QDIM;
#pragma unroll
  for (int i = 0; i < 2; ++i) {
    int u = t + i * 256; int rr = u >> 3, c8 = (u & 7) * 8;
    bf16x8 v = load8(&in[(size_t)(r0 + rr) * HID + c0 + c8]);
#pragma unroll
    for (int j = 0; j < 8; ++j) T[c8 + j][rr] = v[j];
  }
  __syncthreads();
#pragma unroll
  for (int i = 0; i < 2; ++i) {
    int u = t + i * 256; int cr = u >> 3, r8 = (u & 7) * 8;
    bf16x8 v;
#pragma unroll
    for (int j = 0; j < 8; ++j) v[j] = T[cr][r8 + j];
    *(bf16x8*)&o[(size_t)(c0 + cr) * QDIM + r0 + r8] = v;
  }
}

// ------- 128x128 MFMA GEMM, BK=64, both-sides XOR swizzle (R8 config) ------
// C = A[M,K] @ BT[N,K]^T. bf16 A/B; LDS [128][64] per matrix (32KB total).
// MEASURED R8: 69.1us, conflicts=0, MfmaUtil 30.5%, Occupancy 31%.
// R10 showed BK=128 is past the occupancy cliff (18% occ, +9.5us) -> BK=64
// is the occupancy-neutral sweet spot for this 2-phase structure.
// Swizzle (rule #21): linear gll16 dest + inverse-permuted SOURCE chunk
// (cg = c ^ (r&7), within the 128B row window) + XOR on fragment reads.
// QSM: fused per-head softmax*SCALE over d (quad-group shfl_xor reduce).
// C/D layout (validated): row=(lane>>4)*4+reg, col=lane&15.
template <typename OT, bool QSM>
__global__ __launch_bounds__(256, 2) void gemm128(
    const bf16_t* __restrict__ A, int lda,
    const bf16_t* __restrict__ BT, int ldb,
    OT* __restrict__ C, int ldc,
    const float* __restrict__ bias, int K) {
  __shared__ bf16_t As[128 * 64];   // 16KB
  __shared__ bf16_t Bs[128 * 64];   // 16KB
  // XCD-aware chunked swizzle (nwg % 8 == 0 for all launches here)
  int nwg = gridDim.x * gridDim.y;
  int wg = blockIdx.y * gridDim.x + blockIdx.x;
  int sw = (wg & 7) * (nwg >> 3) + (wg >> 3);
  int bx = sw % gridDim.x, by = sw / gridDim.x;

  int m0 = by * 128, n0 = bx * 128;
  int t = threadIdx.x;
  int w = t >> 6, lane = t & 63;
  int wm = (w >> 1) * 64, wn = (w & 1) * 64;
  int lr = lane & 15;

  floatx4 acc[4][4];
#pragma unroll
  for (int mi = 0; mi < 4; ++mi)
#pragma unroll
    for (int ni = 0; ni < 4; ++ni) acc[mi][ni] = (floatx4){0.f, 0.f, 0.f, 0.f};

  for (int k0 = 0; k0 < K; k0 += 64) {
#pragma unroll
    for (int i = 0; i < 4; ++i) {
      int idx = i * 256 + t;            // 16B-chunk id in 128x64 tile
      int r = idx >> 3, c = idx & 7;
      int cg = c ^ (r & 7);             // inverse-swizzled source chunk
      char* la = (char*)As + i * 4096 + w * 1024;   // wave-uniform dest
      char* lb = (char*)Bs + i * 4096 + w * 1024;
      gll16(A  + (size_t)(m0 + r) * lda + k0 + cg * 8, la);
      gll16(BT + (size_t)(n0 + r) * ldb + k0 + cg * 8, lb);
    }
    __syncthreads();   // compiler drains vmcnt(0) before barrier
#pragma unroll
    for (int s = 0; s < 2; ++s) {
      int ci = s * 4 + (lane >> 4);     // k-chunk index within the 64-slice
      bf16x8 af[4], bfr[4];
#pragma unroll
      for (int mi = 0; mi < 4; ++mi) {
        int row = wm + mi * 16 + lr;
        af[mi] = *(const bf16x8*)((char*)As + row * 128 + ((ci ^ (row & 7)) * 16));
      }
#pragma unroll
      for (int ni = 0; ni < 4; ++ni) {
        int row = wn + ni * 16 + lr;
        bfr[ni] = *(const bf16x8*)((char*)Bs + row * 128 + ((ci ^ (row & 7)) * 16));
      }
#pragma unroll
      for (int mi = 0; mi < 4; ++mi)
#pragma unroll
        for (int ni = 0; ni < 4; ++ni)
          acc[mi][ni] = __builtin_amdgcn_mfma_f32_16x16x32_bf16(af[mi], bfr[ni], acc[mi][ni], 0, 0, 0);
    }
    __syncthreads();
  }

  if (QSM && n0 < HID) {
    // fused softmax over the wave's 64-col head, per output row
#pragma unroll
    for (int mi = 0; mi < 4; ++mi)
#pragma unroll
      for (int r = 0; r < 4; ++r) {
        float m = -1e30f;
#pragma unroll
        for (int ni = 0; ni < 4; ++ni) m = fmaxf(m, acc[mi][ni][r]);
#pragma unroll
        for (int off = 1; off < 16; off <<= 1) m = fmaxf(m, __shfl_xor(m, off));
        float e0 = __expf(acc[mi][0][r] - m), e1 = __expf(acc[mi][1][r] - m);
        float e2 = __expf(acc[mi][2][r] - m), e3 = __expf(acc[mi][3][r] - m);
        float s = e0 + e1 + e2 + e3;
#pragma unroll
        for (int off = 1; off < 16; off <<= 1) s += __shfl_xor(s, off);
        float inv = 0.125f / s;
        acc[mi][0][r] = e0 * inv; acc[mi][1][r] = e1 * inv;
        acc[mi][2][r] = e2 * inv; acc[mi][3][r] = e3 * inv;
      }
  }

  int quad = (lane >> 4);
#pragma unroll
  for (int ni = 0; ni < 4; ++ni) {
    int gc = n0 + wn + ni * 16 + lr;
    float bv = (!QSM && bias) ? bias[gc] : 0.f;
#pragma unroll
    for (int mi = 0; mi < 4; ++mi)
#pragma unroll
      for (int r = 0; r < 4; ++r) {
        int gr = m0 + wm + mi * 16 + quad * 4 + r;
        store_out(&C[(size_t)gr * ldc + gc], acc[mi][ni][r] + bv);
      }
  }
}

// ------- 256x128 MFMA GEMM for the final projection, BK=64 + swizzle -------
// out[gr][gc] = sum_k q_sm[gr][k] * W2T[b][gc][k] + bo[gc],  b = gr/4096.
// 512 blocks (one clean pass at 2 blocks/CU; LDS 48KB -> 96KB/CU ok).
// K=512 -> 8 drain periods; both-sides swizzle (R10: part of the -15us win).
__global__ __launch_bounds__(256, 2) void gemm_out(
    const bf16_t* __restrict__ A,            // qkv (q cols 0..511), lda=QKV_LD
    const bf16_t* __restrict__ W2T,          // [b][1024][512] bf16
    float* __restrict__ C,                   // out [16384][1024] f32
    const float* __restrict__ bias) {
  __shared__ bf16_t As[256 * 64];   // 32KB
  __shared__ bf16_t Bs[128 * 64];   // 16KB
  int nwg = gridDim.x * gridDim.y;              // 512
  int wg = blockIdx.y * gridDim.x + blockIdx.x;
  int sw = (wg & 7) * (nwg >> 3) + (wg >> 3);
  int bx = sw % gridDim.x, by = sw / gridDim.x; // bx 0..7, by 0..63
  int m0 = by * 256, n0 = bx * 128;
  const bf16_t* BT = W2T + (size_t)(by >> 4) * QDIM * HID;  // batch = by/16
  int t = threadIdx.x;
  int w = t >> 6, lane = t & 63;
  int lr = lane & 15;

  floatx4 acc[4][8];
#pragma unroll
  for (int mi = 0; mi < 4; ++mi)
#pragma unroll
    for (int ni = 0; ni < 8; ++ni) acc[mi][ni] = (floatx4){0.f, 0.f, 0.f, 0.f};

  for (int k0 = 0; k0 < HID; k0 += 64) {
#pragma unroll
    for (int i = 0; i < 8; ++i) {     // A: 256x64 bf16 = 32KB
      int idx = i * 256 + t; int r = idx >> 3, c = idx & 7;
      int cg = c ^ (r & 7);
      gll16(A + (size_t)(m0 + r) * QKV_LD + k0 + cg * 8,
            (char*)As + i * 4096 + w * 1024);
    }
#pragma unroll
    for (int i = 0; i < 4; ++i) {     // B: 128x64 bf16 = 16KB
      int idx = i * 256 + t; int r = idx >> 3, c = idx & 7;
      int cg = c ^ (r & 7);
      gll16(BT + (size_t)(n0 + r) * HID + k0 + cg * 8,
            (char*)Bs + i * 4096 + w * 1024);
    }
    __syncthreads();
#pragma unroll
    for (int s = 0; s < 2; ++s) {
      int ci = s * 4 + (lane >> 4);
      bf16x8 af[4];
#pragma unroll
      for (int mi = 0; mi < 4; ++mi) {
        int row = w * 64 + mi * 16 + lr;
        af[mi] = *(const bf16x8*)((char*)As + row * 128 + ((ci ^ (row & 7)) * 16));
      }
#pragma unroll
      for (int ni = 0; ni < 8; ++ni) {
        int row = ni * 16 + lr;
        bf16x8 bfr = *(const bf16x8*)((char*)Bs + row * 128 + ((ci ^ (row & 7)) * 16));
#pragma unroll
        for (int mi = 0; mi < 4; ++mi)
          acc[mi][ni] = __builtin_amdgcn_mfma_f32_16x16x32_bf16(af[mi], bfr, acc[mi][ni], 0, 0, 0);
      }
    }
    __syncthreads();
  }
  int quad = (lane >> 4);
#pragma unroll
  for (int ni = 0; ni < 8; ++ni) {
    int gc = n0 + ni * 16 + lr;
    float bv = bias[gc];
#pragma unroll
    for (int mi = 0; mi < 4; ++mi)
#pragma unroll
      for (int r = 0; r < 4; ++r) {
        int gr = m0 + w * 64 + mi * 16 + quad * 4 + r;
        C[(size_t)gr * QDIM + gc] = acc[mi][ni][r] + bv;
      }
  }
}

// ------ context MFMA (no-max exp + fused denominator via ones-MFMA) --------
// cPart[chunk][bh][d][e] = sum_{n in chunk} exp(k[d,n]) * v[e,n]
// sPart[chunk][bh][d]    = sum_{n in chunk} exp(k[d,n])
// Transpose staging XOR-swizzled (R8: conflicts -> 0).
__global__ __launch_bounds__(256) void context_mfma(
    const bf16_t* __restrict__ qkv, float* __restrict__ cPart,
    float* __restrict__ sPart) {
  int chunk = blockIdx.x;  // 0..15 (256 n each)
  int bh = blockIdx.y;     // 0..31
  int b = bh >> 3, h = bh & 7;
  __shared__ bf16_t ksh[64 * 72];  // [d][n_local], row stride 144B, swizzled
  __shared__ bf16_t vsh[64 * 72];  // [e][n_local]
  int t = threadIdx.x;
  int w = t >> 6, lane = t & 63;
  int lr = lane & 15, lk = (lane >> 4) * 8;
  floatx4 acc[4];
  floatx4 accs = (floatx4){0.f, 0.f, 0.f, 0.f};
#pragma unroll
  for (int ni = 0; ni < 4; ++ni) acc[ni] = (floatx4){0.f, 0.f, 0.f, 0.f};
  bf16x8 ones;
#pragma unroll
  for (int j = 0; j < 8; ++j) ones[j] = f2b(1.f);

  for (int nt = 0; nt < 4; ++nt) {
    int n0 = chunk * 256 + nt * 64;
    __syncthreads();
#pragma unroll
    for (int i = 0; i < 2; ++i) {
      int u = t + i * 256; int nr = u >> 3, d8 = (u & 7) * 8;
      const bf16_t* base = qkv + (size_t)(b * NN + n0 + nr) * QKV_LD + h * 64 + d8;
      bf16x8 kv = *(const bf16x8*)(base + HID);
      bf16x8 vv = *(const bf16x8*)(base + 2 * HID);
#pragma unroll
      for (int j = 0; j < 8; ++j) {
        int d = d8 + j;
        size_t byo = ((size_t)d * 144 + nr * 2) ^ (((d >> 3) & 7) << 4);
        *(bf16_t*)((char*)ksh + byo) = f2b(__expf(b2f(kv[j])));
        *(bf16_t*)((char*)vsh + byo) = vv[j];
      }
    }
    __syncthreads();
#pragma unroll
    for (int s = 0; s < 2; ++s) {
      int arow = w * 16 + lr;
      size_t ab = ((size_t)arow * 144 + (s * 32 + lk) * 2) ^ (((arow >> 3) & 7) << 4);
      bf16x8 a = *(const bf16x8*)((char*)ksh + ab);
#pragma unroll
      for (int ni = 0; ni < 4; ++ni) {
        int brow = ni * 16 + lr;
        size_t bb = ((size_t)brow * 144 + (s * 32 + lk) * 2) ^ (((brow >> 3) & 7) << 4);
        bf16x8 bfr = *(const bf16x8*)((char*)vsh + bb);
        acc[ni] = __builtin_amdgcn_mfma_f32_16x16x32_bf16(a, bfr, acc[ni], 0, 0, 0);
      }
      accs = __builtin_amdgcn_mfma_f32_16x16x32_bf16(a, ones, accs, 0, 0, 0);
    }
  }
  float* op = cPart + (size_t)(chunk * 32 + bh) * 4096;
  int quad = lane >> 4;
#pragma unroll
  for (int ni = 0; ni < 4; ++ni)
#pragma unroll
    for (int r = 0; r < 4; ++r)
      op[(w * 16 + quad * 4 + r) * 64 + ni * 16 + lr] = acc[ni][r];
  if (lr == 0) {   // cols of accs identical; 4 lanes/wave cover 16 rows each
#pragma unroll
    for (int r = 0; r < 4; ++r)
      sPart[(size_t)(chunk * 32 + bh) * 64 + w * 16 + quad * 4 + r] = accs[r];
  }
}

// ------ fold ctx into Wo:  W2T[b][c][h*64+d] = sum_e ctx[bh][d][e]*Wo[h*64+e][c]
// Fused: cPart 16-partial combine + sPart denominator merge + direct f32 Wo
// staging (transposed in LDS).
__global__ __launch_bounds__(256) void ctx2w2(
    const float* __restrict__ cPart, const float* __restrict__ sPart,
    const float* __restrict__ Wo, bf16_t* __restrict__ W2T) {
  int cchunk = blockIdx.x; // 0..7 (128 c-rows each)
  int bh = blockIdx.y;     // 0..31
  int b = bh >> 3, h = bh & 7;
  __shared__ float cs[64][65];    // [d][e], padded vs bank conflicts
  __shared__ float wsf[128][65];  // [c_loc][e]
  __shared__ float sinv[64];
  int t = threadIdx.x;
  if (t < 64) {
    float s = 0.f;
#pragma unroll 4
    for (int p = 0; p < 16; ++p) s += sPart[(size_t)(p * 32 + bh) * 64 + t];
    sinv[t] = 1.f / s;
  }
  __syncthreads();
  // stage cs = (sum of 16 cPart partials) * sinv[d]
#pragma unroll
  for (int i = 0; i < 4; ++i) {
    int f4 = t + i * 256;           // float4 index within 64x64
    float4 s = make_float4(0.f, 0.f, 0.f, 0.f);
#pragma unroll 4
    for (int p = 0; p < 16; ++p) {
      float4 v = *(const float4*)&cPart[(size_t)(p * 32 + bh) * 4096 + f4 * 4];
      s.x += v.x; s.y += v.y; s.z += v.z; s.w += v.w;
    }
    int u = f4 * 4; int d = u >> 6, e = u & 63;
    float iv = sinv[d];
    cs[d][e] = s.x * iv; cs[d][e + 1] = s.y * iv;
    cs[d][e + 2] = s.z * iv; cs[d][e + 3] = s.w * iv;
  }
  // stage Wo slice transposed: wsf[c_loc][e] = Wo[h*64+e][cchunk*128+c_loc]
#pragma unroll
  for (int i = 0; i < 8; ++i) {
    int u = t + i * 256;            // 2048 float4s = 64 e x 32 c-quads
    int e = u >> 5, c4 = u & 31;
    float4 v = *(const float4*)&Wo[(size_t)(h * 64 + e) * QDIM + cchunk * 128 + c4 * 4];
    wsf[c4 * 4 + 0][e] = v.x; wsf[c4 * 4 + 1][e] = v.y;
    wsf[c4 * 4 + 2][e] = v.z; wsf[c4 * 4 + 3][e] = v.w;
  }
  __syncthreads();
  int d = t & 63;        // lane -> d (cs row, conflict-free via pad)
  int cq = t >> 6;       // wave -> c quarter
  float rd[64];
#pragma unroll
  for (int e = 0; e < 64; ++e) rd[e] = cs[d][e];
#pragma unroll 4
  for (int ci = 0; ci < 32; ++ci) {
    int cl = cq * 32 + ci;   // wave-uniform -> wsf row broadcast
    float s = 0.f;
#pragma unroll
    for (int e = 0; e < 64; ++e) s += rd[e] * wsf[cl][e];
    W2T[((size_t)b * 1024 + cchunk * 128 + cl) * 512 + h * 64 + d] = f2b(s);
  }
}

// ---------------- launch ---------------------------------------------------
extern "C" void kernel_launch(void* const* d_in, const int* in_sizes, int n_in,
                              void* d_out, int out_size, void* d_ws, size_t ws_size,
                              hipStream_t stream) {
  const float* x  = (const float*)d_in[0];
  const float* Wq = (const float*)d_in[1];
  const float* Wk = (const float*)d_in[2];
  const float* Wv = (const float*)d_in[3];
  const float* Wo = (const float*)d_in[4];
  const float* bo = (const float*)d_in[5];
  float* out = (float*)d_out;
  char* ws = (char*)d_ws;

  bf16_t* qkv   = (bf16_t*)(ws + OFF_QKV);
  bf16_t* WTall = (bf16_t*)(ws + OFF_WT);
  float*  cPart = (float*)(ws + OFF_CP);
  float*  sPart = (float*)(ws + OFF_SPT);
  bf16_t* W2T   = (bf16_t*)(ws + OFF_W2);
  bf16_t* xb    = (bf16_t*)(ws + OFF_XB);   // aliases cPart..; dead after QKV gemm

  // x downconvert + QKV weight transposes (one launch)
  prep<<<8576, 256, 0, stream>>>(x, Wq, Wk, Wv, xb, WTall);

  // QKV projection + fused q-softmax: [16384,1024](bf16) @ [1024,1536] -> bf16
  gemm128<bf16_t, true><<<dim3(12, 128), 256, 0, stream>>>(
      xb, QDIM, WTall, QDIM, qkv, QKV_LD, nullptr, QDIM);

  // context via MFMA (no-max exp, fused denominator; xb now dead -> cPart ok)
  context_mfma<<<dim3(16, 32), 256, 0, stream>>>(qkv, cPart, sPart);

  // fold ctx into Wo (per batch), fused combine+normalize: W2T[b]=(ctx_b@Wo)^T
  ctx2w2<<<dim3(8, 32), 256, 0, stream>>>(cPart, sPart, Wo, W2T);

  // final projection + bias: 256x128 tiles, batch folded into row-tile index
  gemm_out<<<dim3(8, 64), 256, 0, stream>>>(qkv, W2T, out, bo);
}